// Round 8
// baseline (38.888 us; speedup 1.0000x reference)
//
#include <hip/hip_runtime.h>
#include <hip/hip_bf16.h>
#include <cmath>

#define B_SZ 4096
#define N_SZ 8192
#define D_SZ 256
#define EPS 1e-8f
// zn is stored as fp8 e4m3 scaled by 16 -> acc = 256*cos.
// exp(sim-2) with sim = 2*cos = acc/128:  exp2( acc*log2e/128 - 2*log2e )
#define EXPC 0.01127105500694503f      // log2(e)/128
#define EXPB -2.8853900817779268f      // -2*log2(e)

typedef __attribute__((ext_vector_type(4))) float f32x4;
typedef __attribute__((ext_vector_type(4))) int   i32x4;
typedef __attribute__((ext_vector_type(8))) int   i32x8;

// fp8 k-segment-transposed panel layout (1 byte/elem):
//   byte(row,k) = (row>>6)*16384 + (k>>4)*1024 + (row&63)*16 + (k&15)
// panel = 64 rows x 256 k = 16 KB. One K=128 MFMA operand (32 fp8) = two
// 16-B loads 1024 B apart.

// ---- Kernel 1: norms + pos (fp32 exact) + fp8 ZN. One wave per pair (i,i+B). ----
__global__ __launch_bounds__(256) void prep_kernel(const float* __restrict__ zi,
                                                   const float* __restrict__ zj,
                                                   char* __restrict__ znb,
                                                   float* __restrict__ pos) {
    const int wave = threadIdx.x >> 6, lane = threadIdx.x & 63;
    const int i = blockIdx.x * 4 + wave;               // 0..B-1
    float4 a = reinterpret_cast<const float4*>(zi + (size_t)i * D_SZ)[lane];
    float4 b = reinterpret_cast<const float4*>(zj + (size_t)i * D_SZ)[lane];
    float ssa = a.x * a.x + a.y * a.y + a.z * a.z + a.w * a.w;
    float ssb = b.x * b.x + b.y * b.y + b.z * b.z + b.w * b.w;
    float dab = a.x * b.x + a.y * b.y + a.z * b.z + a.w * b.w;
    #pragma unroll
    for (int off = 32; off; off >>= 1) {
        ssa += __shfl_xor(ssa, off, 64);
        ssb += __shfl_xor(ssb, off, 64);
        dab += __shfl_xor(dab, off, 64);
    }
    const float invna = 1.0f / fmaxf(sqrtf(ssa), EPS);
    const float invnb = 1.0f / fmaxf(sqrtf(ssb), EPS);
    if (lane == 0) {
        float p = dab * invna * invnb * 2.0f;
        pos[i] = p;
        pos[i + B_SZ] = p;
    }
    // lane covers k = 4*lane .. 4*lane+3; seg = lane>>2, in-seg byte = (lane&3)*4.
    const float sa = invna * 16.0f, sb = invnb * 16.0f;
    const int koff = (lane >> 2) * 1024 + (lane & 3) * 4;
    {
        int pk = __builtin_amdgcn_cvt_pk_fp8_f32(a.x * sa, a.y * sa, 0, false);
        pk     = __builtin_amdgcn_cvt_pk_fp8_f32(a.z * sa, a.w * sa, pk, true);
        *reinterpret_cast<int*>(znb + (size_t)(i >> 6) * 16384 + koff + (i & 63) * 16) = pk;
    }
    {
        const int r = i + B_SZ;
        int pk = __builtin_amdgcn_cvt_pk_fp8_f32(b.x * sb, b.y * sb, 0, false);
        pk     = __builtin_amdgcn_cvt_pk_fp8_f32(b.z * sb, b.w * sb, pk, true);
        *reinterpret_cast<int*>(znb + (size_t)(r >> 6) * 16384 + koff + (r & 63) * 16) = pk;
    }
}

// ---- Kernel 2: SYMMETRIC barrier-free fp8 K=128 sim-GEMM + exp-sum ----
// Only upper-triangle tiles (rt <= chunk): 528 of 1024 blocks do work.
// Off-diagonal tiles scatter BOTH row-sums (rows of rt-tile -> slot chunk)
// and col-sums (rows of chunk-tile -> slot rt). Per row in tile t the slots
// {t..31} (row-sums) and {0..t-1} (col-sums) are disjoint and complete ->
// plain stores, deterministic, no zero-init.
__global__ __launch_bounds__(256, 3) void simlse_kernel(const char* __restrict__ znb,
                                                        float* __restrict__ partial) {
    const int t = threadIdx.x;
    const int wave = t >> 6, lane = t & 63;
    const int rt = blockIdx.x >> 5;              // row tile 0..31 (256 rows)
    const int chunk = blockIdx.x & 31;           // col tile 0..31 (256 cols)
    if (rt > chunk) return;                      // lower triangle: by symmetry
    const bool offdiag = (rt != chunk);
    __shared__ float cs[4][256];                 // per-wave col-sums

    const int rl = lane & 15;                    // A-row / B-col within fragment
    const int kg = lane >> 4;                    // 32-elem k-block index
    const int i0 = rt * 256 + wave * 64;         // wave's first row

    // A panel: 4 rowgroups x 2 k-chunks of 128; 8 dwords (32 fp8) per frag.
    const char* ap = znb + (size_t)(rt * 4 + wave) * 16384 + rl * 16;
    i32x8 afrag[4][2];
    #pragma unroll
    for (int g = 0; g < 4; ++g)
        #pragma unroll
        for (int kc = 0; kc < 2; ++kc) {
            i32x4 lo = *reinterpret_cast<const i32x4*>(
                ap + (kc * 8 + kg * 2) * 1024 + g * 256);
            i32x4 hi = *reinterpret_cast<const i32x4*>(
                ap + (kc * 8 + kg * 2 + 1) * 1024 + g * 256);
            afrag[g][kc] = __builtin_shufflevector(lo, hi, 0, 1, 2, 3, 4, 5, 6, 7);
        }

    float s_acc[4][4];
    #pragma unroll
    for (int g = 0; g < 4; ++g)
        #pragma unroll
        for (int r = 0; r < 4; ++r) s_acc[g][r] = 0.0f;

    // B fragment base for this lane; per f-group of 16 cols:
    //   addr = bp0 + (f>>2)*16384 + (f&3)*256  (+8192 for kc=1, +1024 for hi half)
    const char* bp0 = znb + (size_t)chunk * 4 * 16384 + kg * 2048 + rl * 16;

    i32x4 nb0 = *reinterpret_cast<const i32x4*>(bp0);
    i32x4 nb1 = *reinterpret_cast<const i32x4*>(bp0 + 1024);
    i32x4 nb2 = *reinterpret_cast<const i32x4*>(bp0 + 8192);
    i32x4 nb3 = *reinterpret_cast<const i32x4*>(bp0 + 9216);

    #pragma unroll 1
    for (int f = 0; f < 16; ++f) {
        i32x8 bf0 = __builtin_shufflevector(nb0, nb1, 0, 1, 2, 3, 4, 5, 6, 7);
        i32x8 bf1 = __builtin_shufflevector(nb2, nb3, 0, 1, 2, 3, 4, 5, 6, 7);
        if (f < 15) {                           // prefetch next f-group
            const char* bq = bp0 + ((f + 1) >> 2) * 16384 + ((f + 1) & 3) * 256;
            nb0 = *reinterpret_cast<const i32x4*>(bq);
            nb1 = *reinterpret_cast<const i32x4*>(bq + 1024);
            nb2 = *reinterpret_cast<const i32x4*>(bq + 8192);
            nb3 = *reinterpret_cast<const i32x4*>(bq + 9216);
        }
        f32x4 acc[4];
        #pragma unroll
        for (int g = 0; g < 4; ++g) acc[g] = (f32x4){0.f, 0.f, 0.f, 0.f};
        #pragma unroll
        for (int g = 0; g < 4; ++g)             // kc0: 4 independent MFMAs
            asm("v_mfma_f32_16x16x128_f8f6f4 %0, %1, %2, %0"
                : "+v"(acc[g]) : "v"(afrag[g][0]), "v"(bf0));
        #pragma unroll
        for (int g = 0; g < 4; ++g)             // kc1: accumulate
            asm("v_mfma_f32_16x16x128_f8f6f4 %0, %1, %2, %0"
                : "+v"(acc[g]) : "v"(afrag[g][1]), "v"(bf1));
        asm volatile("s_nop 7");                // MFMA->VALU read hazard guard
        float cthr = 0.0f;                      // this thread's col contribution
        #pragma unroll
        for (int g = 0; g < 4; ++g)
            #pragma unroll
            for (int r = 0; r < 4; ++r) {
                float e = __builtin_amdgcn_exp2f(fmaf(acc[g][r], EXPC, EXPB));
                s_acc[g][r] += e;
                cthr += e;
            }
        // col-sum over the 4 kg groups (lanes rl, rl+16, rl+32, rl+48)
        cthr += __shfl_xor(cthr, 16, 64);
        cthr += __shfl_xor(cthr, 32, 64);
        if (offdiag && lane < 16)
            cs[wave][(f >> 2) * 64 + (f & 3) * 16 + rl] = cthr;
    }

    // Row-sums over the 16 col-lanes (rl); rows i0 + g*16 + kg*4 + r -> slot chunk.
    #pragma unroll
    for (int g = 0; g < 4; ++g)
        #pragma unroll
        for (int r = 0; r < 4; ++r) {
            float v = s_acc[g][r];
            #pragma unroll
            for (int off = 1; off < 16; off <<= 1) v += __shfl_xor(v, off, 64);
            if (rl == 0)
                partial[chunk * N_SZ + i0 + g * 16 + kg * 4 + r] = v;
        }

    // Col-sums: combine 4 waves, write rows of the chunk-tile -> slot rt.
    if (offdiag) {
        __syncthreads();
        float v = cs[0][t] + cs[1][t] + cs[2][t] + cs[3][t];
        partial[rt * N_SZ + chunk * 256 + t] = v;
    }
}

// ---- Kernel 3: per-row lse - pos, 32 block partials ----
__global__ __launch_bounds__(256) void rowsum_kernel(const float* __restrict__ partial,
                                                     const float* __restrict__ pos,
                                                     float* __restrict__ bpart) {
    const int row = blockIdx.x * 256 + threadIdx.x;
    float s = -1.0f;                       // remove diagonal exp(~0)=1
    #pragma unroll
    for (int c = 0; c < 32; ++c) s += partial[c * N_SZ + row];
    float acc = 2.0f + logf(s) - pos[row];
    #pragma unroll
    for (int off = 32; off; off >>= 1) acc += __shfl_xor(acc, off, 64);
    __shared__ float w[4];
    if ((threadIdx.x & 63) == 0) w[threadIdx.x >> 6] = acc;
    __syncthreads();
    if (threadIdx.x == 0) bpart[blockIdx.x] = w[0] + w[1] + w[2] + w[3];
}

__global__ __launch_bounds__(64) void finsum_kernel(const float* __restrict__ bpart,
                                                    float* __restrict__ out) {
    float v = threadIdx.x < 32 ? bpart[threadIdx.x] : 0.0f;
    #pragma unroll
    for (int off = 32; off; off >>= 1) v += __shfl_xor(v, off, 64);
    if (threadIdx.x == 0) out[0] = v / (float)N_SZ;
}

extern "C" void kernel_launch(void* const* d_in, const int* in_sizes, int n_in,
                              void* d_out, int out_size, void* d_ws, size_t ws_size,
                              hipStream_t stream) {
    const float* zi = (const float*)d_in[0];
    const float* zj = (const float*)d_in[1];

    char* ws = (char*)d_ws;
    char* znb      = ws;                                   // 2 MB fp8 k-seg layout
    float* pos     = (float*)(ws + 2097152);               // 32 KB
    float* partial = (float*)(ws + 2097152 + 32768);       // 32*8192*4 = 1 MB
    float* bpart   = (float*)(ws + 2097152 + 32768 + 1048576); // 128 B
    float* out = (float*)d_out;

    prep_kernel<<<B_SZ / 4, 256, 0, stream>>>(zi, zj, znb, pos);
    simlse_kernel<<<1024, 256, 0, stream>>>(znb, partial);
    rowsum_kernel<<<32, 256, 0, stream>>>(partial, pos, bpart);
    finsum_kernel<<<1, 64, 0, stream>>>(bpart, out);
}

// Round 9
// 35.123 us; speedup vs baseline: 1.1072x; 1.1072x over previous
//
#include <hip/hip_runtime.h>
#include <hip/hip_bf16.h>
#include <cmath>

#define B_SZ 4096
#define N_SZ 8192
#define D_SZ 256
#define EPS 1e-8f
// zn is stored as fp8 e4m3 scaled by 16 -> acc = 256*cos.
// exp(sim-2) with sim = 2*cos = acc/128:  exp2( acc*log2e/128 - 2*log2e )
#define EXPC 0.01127105500694503f      // log2(e)/128
#define EXPB -2.8853900817779268f      // -2*log2(e)

typedef __attribute__((ext_vector_type(4))) float f32x4;
typedef __attribute__((ext_vector_type(4))) int   i32x4;
typedef __attribute__((ext_vector_type(8))) int   i32x8;

// fp8 k-segment-transposed panel layout (1 byte/elem):
//   byte(row,k) = (row>>6)*16384 + (k>>4)*1024 + (row&63)*16 + (k&15)
// panel = 64 rows x 256 k = 16 KB. One K=128 MFMA operand (32 fp8) = two
// 16-B loads 1024 B apart.

// ---- Kernel 1: norms + pos (fp32 exact) + fp8 ZN. One wave per pair (i,i+B). ----
__global__ __launch_bounds__(256) void prep_kernel(const float* __restrict__ zi,
                                                   const float* __restrict__ zj,
                                                   char* __restrict__ znb,
                                                   float* __restrict__ pos) {
    const int wave = threadIdx.x >> 6, lane = threadIdx.x & 63;
    const int i = blockIdx.x * 4 + wave;               // 0..B-1
    float4 a = reinterpret_cast<const float4*>(zi + (size_t)i * D_SZ)[lane];
    float4 b = reinterpret_cast<const float4*>(zj + (size_t)i * D_SZ)[lane];
    float ssa = a.x * a.x + a.y * a.y + a.z * a.z + a.w * a.w;
    float ssb = b.x * b.x + b.y * b.y + b.z * b.z + b.w * b.w;
    float dab = a.x * b.x + a.y * b.y + a.z * b.z + a.w * b.w;
    #pragma unroll
    for (int off = 32; off; off >>= 1) {
        ssa += __shfl_xor(ssa, off, 64);
        ssb += __shfl_xor(ssb, off, 64);
        dab += __shfl_xor(dab, off, 64);
    }
    const float invna = 1.0f / fmaxf(sqrtf(ssa), EPS);
    const float invnb = 1.0f / fmaxf(sqrtf(ssb), EPS);
    if (lane == 0) {
        float p = dab * invna * invnb * 2.0f;
        pos[i] = p;
        pos[i + B_SZ] = p;
    }
    // lane covers k = 4*lane .. 4*lane+3; seg = lane>>2, in-seg byte = (lane&3)*4.
    const float sa = invna * 16.0f, sb = invnb * 16.0f;
    const int koff = (lane >> 2) * 1024 + (lane & 3) * 4;
    {
        int pk = __builtin_amdgcn_cvt_pk_fp8_f32(a.x * sa, a.y * sa, 0, false);
        pk     = __builtin_amdgcn_cvt_pk_fp8_f32(a.z * sa, a.w * sa, pk, true);
        *reinterpret_cast<int*>(znb + (size_t)(i >> 6) * 16384 + koff + (i & 63) * 16) = pk;
    }
    {
        const int r = i + B_SZ;
        int pk = __builtin_amdgcn_cvt_pk_fp8_f32(b.x * sb, b.y * sb, 0, false);
        pk     = __builtin_amdgcn_cvt_pk_fp8_f32(b.z * sb, b.w * sb, pk, true);
        *reinterpret_cast<int*>(znb + (size_t)(r >> 6) * 16384 + koff + (r & 63) * 16) = pk;
    }
}

// ---- Kernel 2: SYMMETRIC barrier-free fp8 K=128 sim-GEMM + exp-sum ----
// Compact triangular grid: 528 blocks = upper-triangle tiles (rt <= chunk).
// Off-diagonal tiles scatter BOTH row-sums (slot chunk) and col-sums (slot rt);
// per row in tile t slots {t..31} (row) and {0..t-1} (col) are disjoint+complete.
// Acc ping-pong: exp/col-sum of phase f-1 overlaps MFMAs of phase f.
__global__ __launch_bounds__(256, 2) void simlse_kernel(const char* __restrict__ znb,
                                                        float* __restrict__ partial) {
    const int t = threadIdx.x;
    const int wave = t >> 6, lane = t & 63;

    // Triangular decode: blockIdx.x in [0,528) -> (rt, chunk), rt <= chunk.
    int bid = blockIdx.x, rt = 0;
    #pragma unroll 1
    for (; rt < 32; ++rt) {
        int cnt = 32 - rt;
        if (bid < cnt) break;
        bid -= cnt;
    }
    const int chunk = rt + bid;
    const bool offdiag = (rt != chunk);
    __shared__ float cs[4][256];                 // per-wave col-sums

    const int rl = lane & 15;                    // A-row / B-col within fragment
    const int kg = lane >> 4;                    // 32-elem k-block index
    const int i0 = rt * 256 + wave * 64;         // wave's first row

    // A panel: 4 rowgroups x 2 k-chunks of 128; 8 dwords (32 fp8) per frag.
    const char* ap = znb + (size_t)(rt * 4 + wave) * 16384 + rl * 16;
    i32x8 afrag[4][2];
    #pragma unroll
    for (int g = 0; g < 4; ++g)
        #pragma unroll
        for (int kc = 0; kc < 2; ++kc) {
            i32x4 lo = *reinterpret_cast<const i32x4*>(
                ap + (kc * 8 + kg * 2) * 1024 + g * 256);
            i32x4 hi = *reinterpret_cast<const i32x4*>(
                ap + (kc * 8 + kg * 2 + 1) * 1024 + g * 256);
            afrag[g][kc] = __builtin_shufflevector(lo, hi, 0, 1, 2, 3, 4, 5, 6, 7);
        }

    float s_acc[4][4];
    #pragma unroll
    for (int g = 0; g < 4; ++g)
        #pragma unroll
        for (int r = 0; r < 4; ++r) s_acc[g][r] = 0.0f;

    // B fragment base; per f-group of 16 cols:
    //   addr = bp0 + (f>>2)*16384 + (f&3)*256  (+8192 for kc=1, +1024 for hi half)
    const char* bp0 = znb + (size_t)chunk * 4 * 16384 + kg * 2048 + rl * 16;

    i32x4 nb0 = *reinterpret_cast<const i32x4*>(bp0);
    i32x4 nb1 = *reinterpret_cast<const i32x4*>(bp0 + 1024);
    i32x4 nb2 = *reinterpret_cast<const i32x4*>(bp0 + 8192);
    i32x4 nb3 = *reinterpret_cast<const i32x4*>(bp0 + 9216);

    i32x8 bf0, bf1;
    f32x4 accA[4], accB[4];

    #define PREP_B(F)                                                             \
        {                                                                         \
            bf0 = __builtin_shufflevector(nb0, nb1, 0, 1, 2, 3, 4, 5, 6, 7);      \
            bf1 = __builtin_shufflevector(nb2, nb3, 0, 1, 2, 3, 4, 5, 6, 7);      \
            if ((F) < 15) {                                                       \
                const char* bq = bp0 + (((F) + 1) >> 2) * 16384 +                 \
                                 (((F) + 1) & 3) * 256;                           \
                nb0 = *reinterpret_cast<const i32x4*>(bq);                        \
                nb1 = *reinterpret_cast<const i32x4*>(bq + 1024);                 \
                nb2 = *reinterpret_cast<const i32x4*>(bq + 8192);                 \
                nb3 = *reinterpret_cast<const i32x4*>(bq + 9216);                 \
            }                                                                     \
        }

    #define MFMA8(ACC)                                                            \
        {                                                                         \
            _Pragma("unroll")                                                     \
            for (int g = 0; g < 4; ++g) ACC[g] = (f32x4){0.f, 0.f, 0.f, 0.f};     \
            _Pragma("unroll")                                                     \
            for (int g = 0; g < 4; ++g)                                           \
                asm("v_mfma_f32_16x16x128_f8f6f4 %0, %1, %2, %0"                  \
                    : "+v"(ACC[g]) : "v"(afrag[g][0]), "v"(bf0));                 \
            _Pragma("unroll")                                                     \
            for (int g = 0; g < 4; ++g)                                           \
                asm("v_mfma_f32_16x16x128_f8f6f4 %0, %1, %2, %0"                  \
                    : "+v"(ACC[g]) : "v"(afrag[g][1]), "v"(bf1));                 \
        }

    #define EXPSUM(ACC, F)                                                        \
        {                                                                         \
            float cthr = 0.0f;                                                    \
            _Pragma("unroll")                                                     \
            for (int g = 0; g < 4; ++g)                                           \
                _Pragma("unroll")                                                 \
                for (int r = 0; r < 4; ++r) {                                     \
                    float e = __builtin_amdgcn_exp2f(fmaf(ACC[g][r], EXPC, EXPB)); \
                    s_acc[g][r] += e;                                             \
                    cthr += e;                                                    \
                }                                                                 \
            cthr += __shfl_xor(cthr, 16, 64);                                     \
            cthr += __shfl_xor(cthr, 32, 64);                                     \
            if (offdiag && lane < 16)                                             \
                cs[wave][((F) >> 2) * 64 + ((F) & 3) * 16 + rl] = cthr;           \
        }

    // Pipelined: MFMA(phase f) overlaps EXPSUM(phase f-1).
    PREP_B(0);
    MFMA8(accA);
    #pragma unroll 1
    for (int fo = 0; fo < 7; ++fo) {
        const int f1 = 2 * fo + 1, f2 = 2 * fo + 2;
        PREP_B(f1); MFMA8(accB);
        asm volatile("s_nop 7");
        EXPSUM(accA, f1 - 1);
        PREP_B(f2); MFMA8(accA);
        asm volatile("s_nop 7");
        EXPSUM(accB, f2 - 1);
    }
    PREP_B(15); MFMA8(accB);
    asm volatile("s_nop 7");
    EXPSUM(accA, 14);
    asm volatile("s_nop 7");
    EXPSUM(accB, 15);

    // Row-sums over the 16 col-lanes (rl); rows i0 + g*16 + kg*4 + r -> slot chunk.
    #pragma unroll
    for (int g = 0; g < 4; ++g)
        #pragma unroll
        for (int r = 0; r < 4; ++r) {
            float v = s_acc[g][r];
            #pragma unroll
            for (int off = 1; off < 16; off <<= 1) v += __shfl_xor(v, off, 64);
            if (rl == 0)
                partial[chunk * N_SZ + i0 + g * 16 + kg * 4 + r] = v;
        }

    // Col-sums: combine 4 waves, write rows of the chunk-tile -> slot rt.
    if (offdiag) {
        __syncthreads();
        float v = cs[0][t] + cs[1][t] + cs[2][t] + cs[3][t];
        partial[rt * N_SZ + chunk * 256 + t] = v;
    }
    #undef PREP_B
    #undef MFMA8
    #undef EXPSUM
}

// ---- Kernel 3: per-row lse - pos, 32 block partials ----
__global__ __launch_bounds__(256) void rowsum_kernel(const float* __restrict__ partial,
                                                     const float* __restrict__ pos,
                                                     float* __restrict__ bpart) {
    const int row = blockIdx.x * 256 + threadIdx.x;
    float s = -1.0f;                       // remove diagonal exp(~0)=1
    #pragma unroll
    for (int c = 0; c < 32; ++c) s += partial[c * N_SZ + row];
    float acc = 2.0f + logf(s) - pos[row];
    #pragma unroll
    for (int off = 32; off; off >>= 1) acc += __shfl_xor(acc, off, 64);
    __shared__ float w[4];
    if ((threadIdx.x & 63) == 0) w[threadIdx.x >> 6] = acc;
    __syncthreads();
    if (threadIdx.x == 0) bpart[blockIdx.x] = w[0] + w[1] + w[2] + w[3];
}

__global__ __launch_bounds__(64) void finsum_kernel(const float* __restrict__ bpart,
                                                    float* __restrict__ out) {
    float v = threadIdx.x < 32 ? bpart[threadIdx.x] : 0.0f;
    #pragma unroll
    for (int off = 32; off; off >>= 1) v += __shfl_xor(v, off, 64);
    if (threadIdx.x == 0) out[0] = v / (float)N_SZ;
}

extern "C" void kernel_launch(void* const* d_in, const int* in_sizes, int n_in,
                              void* d_out, int out_size, void* d_ws, size_t ws_size,
                              hipStream_t stream) {
    const float* zi = (const float*)d_in[0];
    const float* zj = (const float*)d_in[1];

    char* ws = (char*)d_ws;
    char* znb      = ws;                                   // 2 MB fp8 k-seg layout
    float* pos     = (float*)(ws + 2097152);               // 32 KB
    float* partial = (float*)(ws + 2097152 + 32768);       // 32*8192*4 = 1 MB
    float* bpart   = (float*)(ws + 2097152 + 32768 + 1048576); // 128 B
    float* out = (float*)d_out;

    prep_kernel<<<B_SZ / 4, 256, 0, stream>>>(zi, zj, znb, pos);
    simlse_kernel<<<528, 256, 0, stream>>>(znb, partial);
    rowsum_kernel<<<32, 256, 0, stream>>>(partial, pos, bpart);
    finsum_kernel<<<1, 64, 0, stream>>>(bpart, out);
}